// Round 12
// baseline (375.383 us; speedup 1.0000x reference)
//
#include <hip/hip_runtime.h>
#include <math.h>

typedef _Float16 f16x4 __attribute__((ext_vector_type(4)));
typedef float    f32x4 __attribute__((ext_vector_type(4)));
typedef float    f32x2 __attribute__((ext_vector_type(2)));

constexpr int kT      = 512;   // sequence length
constexpr int kH      = 16;    // hidden
constexpr int kL      = 8;     // layers
constexpr int kNB     = 4;     // batches/block -> 512 blocks = 2 per CU
constexpr int kC      = 16;    // chunk length (timesteps per stage)
constexpr int kChunks = kT / kC;            // 32
constexpr int kStages = kChunks + kL - 1;   // 39 barriers
constexpr int kRowE   = kNB * kH;           // 64 f16 per chunk-step row

constexpr float kL2E = 1.4426950408889634f;

__device__ __forceinline__ float ex2(float w)  { return __builtin_amdgcn_exp2f(w); }
__device__ __forceinline__ float rcpf(float e) { return __builtin_amdgcn_rcpf(e); }

// Round-20: chunked wavefront (R19 structure) at 4 waves/SIMD.
//  - R19 diagnosis: chunk structure fine, but 2 barrier-aligned waves/SIMD
//    stall simultaneously (VALUBusy 62%, 1150cy/step vs ~650cy issue demand).
//  - fix: kNB=4 -> 512 blocks, 2 dephased blocks/CU, 4 waves/SIMD; per-wave
//    work halves (1 cell/lane = 7 trans), issue demand/SIMD invariant but
//    4 independent chains fill each other's dependency-stall windows.
//  - map (derived from rr8's verified per-gate MFMA layout):
//    A_p row m: wrow=(m&3)*16+4*(m>>2)+p, cols k=4q..4q+3 (identical to rr8)
//    B cols: batch n&3 (duplicated x4); D: lane(n,q) reg r of MFMA_p =
//    gate r of (unit 4q+p, batch n&3); lane ACTIVATES p = n>>2 only.
//  - B2 (h[4q..4q+3][b]) assembled in-register: shfl_xor(4) pairs units,
//    shfl_xor(8) pairs pairs. Recurrence state never touches LDS.
//  - B1: rolling 2-entry prefetch (ds_read_b64, conflict-free); l==0 from
//    f32x2 x-prefetch regs (chunk-deep, vmcnt rides barriers) + shfl_xor(8).
//  - one lgkmcnt(0)+s_barrier per stage (39 total).
__global__ __launch_bounds__(512, 4)
void lstm_ck4(const float* __restrict__ x,
              const float* __restrict__ Wih, const float* __restrict__ Whh,
              const float* __restrict__ bih, const float* __restrict__ bhh,
              const float* __restrict__ Wp,  const float* __restrict__ bpos,
              const float* __restrict__ Wo,  const float* __restrict__ bori,
              float* __restrict__ out)
{
    const int tid  = threadIdx.x;
    const int l    = tid >> 6;        // wave = layer (permanent)
    const int lane = tid & 63;
    const int n    = lane & 15;
    const int q    = lane >> 4;
    const int b    = n & 3;           // batch (cols n, n+4, n+8, n+12 dup)
    const int t4   = n >> 2;          // unit-slot selector (0..3)
    const int p2   = t4 >> 1;         // unit-pair selector
    const int myU  = 4 * q + t4;      // lane's own unit

    __shared__ __align__(16) _Float16 hbuf[2][kL - 1][kC][kNB][kH]; // 28672 B
    __shared__ __align__(16) _Float16 headb[kNB][kH];               // 128 B

    // ---- A fragments + scaled bias C-init (rr8-verified map) ----
    const float asc = ((n & 3) == 2) ? (-2.0f * kL2E) : (-kL2E);
    f16x4 A1[4], A2[4];
    f32x4 bias[4];
    #pragma unroll
    for (int p = 0; p < 4; ++p) {
        const int wrow = (n & 3) * 16 + 4 * (n >> 2) + p;
        const float* w1 = Wih + (size_t)l * 64 * kH + wrow * kH + 4 * q;
        const float* w2 = Whh + (size_t)l * 64 * kH + wrow * kH + 4 * q;
        #pragma unroll
        for (int jj = 0; jj < 4; ++jj) {
            A1[p][jj] = (_Float16)(asc * w1[jj]);
            A2[p][jj] = (_Float16)(asc * w2[jj]);
        }
        #pragma unroll
        for (int r = 0; r < 4; ++r) {   // C-init: gate r of unit 4q+p
            const float sc = (r == 2) ? (-2.0f * kL2E) : (-kL2E);
            const int g0 = l * 64 + r * 16 + 4 * q + p;
            bias[p][r] = sc * (bih[g0] + bhh[g0]);
        }
    }

    // ---- x prefetch (wave 0): f32x2 of units (4q+2p2, +1), batch b ----
    const float* xg = x + ((size_t)(blockIdx.x * kNB + b) * kT) * kH
                        + 4 * q + 2 * p2;
    f32x2 xf[kC];
    if (l == 0) {
        #pragma unroll
        for (int j = 0; j < kC; ++j)
            xf[j] = *(const f32x2*)(xg + (size_t)j * kH);
    }

    f16x4 B2r = { (_Float16)0.f, (_Float16)0.f, (_Float16)0.f, (_Float16)0.f };
    float c0 = 0.f;               // register cell state, whole sequence

    #pragma unroll 1
    for (int s = 0; s < kStages; ++s) {
        const int c = s - l;                      // this wave's chunk
        if ((unsigned)c < (unsigned)kChunks) {    // wave-uniform guard
            const _Float16* rsrc = &hbuf[c & 1][(l > 0) ? (l - 1) : 0][0][b][4 * q];
            _Float16* wdst = &hbuf[c & 1][(l < kL - 1) ? l : 0][0][b][myU];

            // assemble l==0 B1 fragment from xf[j] (compile-time j)
            auto xB1 = [&](int j) -> f16x4 {
                union { _Float16 h[2]; int i; } up;
                up.h[0] = (_Float16)xf[j][0];
                up.h[1] = (_Float16)xf[j][1];
                const int pd = up.i;
                const int od = __shfl_xor(pd, 8, 64);
                union { int i2[2]; f16x4 v; } ua;
                ua.i2[0] = p2 ? od : pd;
                ua.i2[1] = p2 ? pd : od;
                return ua.v;
            };

            f16x4 B1cur;
            if (l > 0) B1cur = *(const f16x4*)(rsrc);
            else       B1cur = xB1(0);

            // ---- 16 register-resident steps, no internal sync ----
            #pragma unroll
            for (int j = 0; j < kC; ++j) {
                f16x4 B1nxt;
                if (j < kC - 1) {
                    if (l > 0) B1nxt = *(const f16x4*)(rsrc + (j + 1) * kRowE);
                    else       B1nxt = xB1(j + 1);
                }

                // input half (off-chain) + chain head (reg-only operands)
                f32x4 dIn0 = __builtin_amdgcn_mfma_f32_16x16x16f16(A1[0], B1cur, bias[0], 0, 0, 0);
                f32x4 dIn1 = __builtin_amdgcn_mfma_f32_16x16x16f16(A1[1], B1cur, bias[1], 0, 0, 0);
                f32x4 dIn2 = __builtin_amdgcn_mfma_f32_16x16x16f16(A1[2], B1cur, bias[2], 0, 0, 0);
                f32x4 dIn3 = __builtin_amdgcn_mfma_f32_16x16x16f16(A1[3], B1cur, bias[3], 0, 0, 0);
                f32x4 d0 = __builtin_amdgcn_mfma_f32_16x16x16f16(A2[0], B2r, dIn0, 0, 0, 0);
                f32x4 d1 = __builtin_amdgcn_mfma_f32_16x16x16f16(A2[1], B2r, dIn1, 0, 0, 0);
                f32x4 d2 = __builtin_amdgcn_mfma_f32_16x16x16f16(A2[2], B2r, dIn2, 0, 0, 0);
                f32x4 d3 = __builtin_amdgcn_mfma_f32_16x16x16f16(A2[3], B2r, dIn3, 0, 0, 0);

                // lane activates only p = t4 (gates of its own cell)
                f32x4 d;
                #pragma unroll
                for (int r = 0; r < 4; ++r) {
                    const float lo = (t4 & 1) ? d1[r] : d0[r];
                    const float hi = (t4 & 1) ? d3[r] : d2[r];
                    d[r] = (t4 & 2) ? hi : lo;
                }

                // ---- 7-trans cell update (verified algebra + clamps) ----
                const float Ei = ex2(fminf(d[0], 40.0f));
                const float Ef = ex2(fminf(d[1], 40.0f));
                const float Eg = ex2(fminf(d[2], 40.0f));
                const float Eo = ex2(fminf(d[3], 60.0f));
                const float Dg = 1.0f + Eg;
                const float Df = 1.0f + Ef;
                const float P1  = fmaf(Ei, Dg, Dg);       // Di*Dg
                const float den = Df * P1;                // Df*Di*Dg
                const float t2  = fmaf(-Eg, Df, Df);      // (1-Eg)*Df
                const float num = fmaf(c0, P1, t2);
                const float cn  = num * rcpf(den);        // sf*c + si*tanh(g)
                c0 = cn;
                const float ac = fminf(cn * (-2.0f * kL2E), 60.0f);
                const float Ec = ex2(ac);
                const float Do = 1.0f + Eo;
                const float R2 = rcpf(fmaf(Do, Ec, Do));
                const float hf = fmaf(-Ec, R2, R2);       // sig(o)*tanh(c)

                const _Float16 h16 = (_Float16)hf;

                // publish h(t) for downstream (off-chain b16 store)
                if (l < kL - 1) wdst[j * kRowE] = h16;
                else if (c == kChunks - 1 && j == kC - 1) headb[b][myU] = h16;

                // B2 assemble in-register: pair units via lane^4, pairs via lane^8
                const int o16 = (int)(unsigned)__builtin_bit_cast(unsigned short, h16);
                const int pp  = __shfl_xor(o16, 4, 64);
                const int pairD = (t4 & 1) ? ((pp & 0xffff) | (o16 << 16))
                                           : (o16 | (pp << 16));
                const int othD  = __shfl_xor(pairD, 8, 64);
                union { int i2[2]; f16x4 v; } ub;
                ub.i2[0] = p2 ? othD : pairD;   // units 4q, 4q+1
                ub.i2[1] = p2 ? pairD : othD;   // units 4q+2, 4q+3
                B2r = ub.v;

                if (j < kC - 1) B1cur = B1nxt;
            }

            // prefetch next x chunk (wave 0; vmcnt rides the barrier)
            if (l == 0 && c + 1 < kChunks) {
                #pragma unroll
                for (int j = 0; j < kC; ++j)
                    xf[j] = *(const f32x2*)(xg + (size_t)((c + 1) * kC + j) * kH);
            }
        }
        // end of stage: drain DS (chunk writes + shfls), one barrier.
        asm volatile("s_waitcnt lgkmcnt(0)\n\ts_barrier" ::: "memory");
    }

    __syncthreads();

    // ---- head: layer-7 h(511) from headb ----
    if (l == kL - 1 && lane < 32) {
        const int bb = lane >> 3;         // batch 0..3
        const int r  = lane & 7;
        if (r < 6) {
            const bool  isP   = (r < 3);
            const float* wrow = isP ? (Wp + r * kH) : (Wo + (r - 3) * kH);
            float acc = isP ? bpos[r] : bori[r - 3];
            #pragma unroll
            for (int u = 0; u < kH; ++u)
                acc = fmaf((float)headb[bb][u], wrow[u], acc);
            if (!isP) {
                const float Et = ex2(-2.0f * kL2E * acc);
                acc = fmaf(2.0f, rcpf(1.0f + Et), -1.0f);
            }
            out[(size_t)(blockIdx.x * kNB + bb) * 6 + r] = acc;
        }
    }
}

extern "C" void kernel_launch(void* const* d_in, const int* in_sizes, int n_in,
                              void* d_out, int out_size, void* d_ws, size_t ws_size,
                              hipStream_t stream) {
    const float* x    = (const float*)d_in[0];
    const float* Wih  = (const float*)d_in[1];
    const float* Whh  = (const float*)d_in[2];
    const float* bih  = (const float*)d_in[3];
    const float* bhh  = (const float*)d_in[4];
    const float* Wp   = (const float*)d_in[5];
    const float* bpos = (const float*)d_in[6];
    const float* Wo   = (const float*)d_in[7];
    const float* bori = (const float*)d_in[8];
    float* out = (float*)d_out;

    const int B = in_sizes[0] / (kT * kH);   // 2048
    lstm_ck4<<<dim3(B / kNB), dim3(512), 0, stream>>>(x, Wih, Whh, bih, bhh,
                                                      Wp, bpos, Wo, bori, out);
}